// Round 1
// baseline (227.554 us; speedup 1.0000x reference)
//
#include <hip/hip_runtime.h>
#include <hip/hip_bf16.h>
#include <stdint.h>

#define LOG2E 1.4426950408889634f

__device__ __forceinline__ float fast_sig(float x) {
    float e = __builtin_amdgcn_exp2f(-LOG2E * x);
    return __builtin_amdgcn_rcpf(1.0f + e);
}
__device__ __forceinline__ float fast_tanh(float x) {
    // tanh(x) = 1 - 2/(exp(2x)+1); args bounded (|c|<=32, gates |x|<~12) -> no overflow
    float e = __builtin_amdgcn_exp2f(2.0f * LOG2E * x);
    return 1.0f - 2.0f * __builtin_amdgcn_rcpf(e + 1.0f);
}
__device__ __forceinline__ float rl_f(float v, int k) {
    return __int_as_float(__builtin_amdgcn_readlane(__float_as_int(v), k));
}

// ---------------- Kernel A: per-char-value tables ----------------
// xproj[v][j] = float4 gate pre-acts (i,f,g,o) of unit j from input char v (incl. both biases)
// hbwd[v][j]  = full backward-direction output for last-char value v
__global__ void build_tables(const float* __restrict__ emb,
                             const float* __restrict__ w_ih_f, const float* __restrict__ b_ih_f,
                             const float* __restrict__ b_hh_f,
                             const float* __restrict__ w_ih_b, const float* __restrict__ b_ih_b,
                             const float* __restrict__ b_hh_b,
                             float* __restrict__ xproj, float* __restrict__ hbwd) {
    int v = blockIdx.x;   // 0..255
    int j = threadIdx.x;  // 0..63
    float e[20];
#pragma unroll
    for (int t = 0; t < 20; ++t) e[t] = emb[v * 20 + t];
    float sf[4], sb[4];
#pragma unroll
    for (int g = 0; g < 4; ++g) {
        int row = g * 64 + j;
        float a = b_ih_f[row] + b_hh_f[row];
        float b = b_ih_b[row] + b_hh_b[row];
#pragma unroll
        for (int t = 0; t < 20; ++t) {
            a += e[t] * w_ih_f[row * 20 + t];
            b += e[t] * w_ih_b[row * 20 + t];
        }
        sf[g] = a; sb[g] = b;
    }
    ((float4*)xproj)[v * 64 + j] = make_float4(sf[0], sf[1], sf[2], sf[3]);
    float cb = fast_sig(sb[0]) * fast_tanh(sb[2]);
    hbwd[v * 64 + j] = fast_sig(sb[3]) * fast_tanh(cb);
}

// ---------------- Prepass: length bucketing ----------------
__global__ void count_lens(const int* __restrict__ chars, int* __restrict__ lens,
                           int* __restrict__ cnt) {
    int w = blockIdx.x * blockDim.x + threadIdx.x;
    if (w >= 16384) return;
    int len = 0;
#pragma unroll
    for (int t = 0; t < 32; ++t) len += (chars[w * 32 + t] != 0);
    lens[w] = len;
    if (len > 0) atomicAdd(&cnt[len], 1);
}

__global__ void scan_buckets(const int* __restrict__ cnt, int* __restrict__ cursor,
                             int* __restrict__ nv) {
    if (threadIdx.x == 0) {
        int run = 0;
        for (int L = 1; L <= 32; ++L) { cursor[L] = run; run += cnt[L]; }
        *nv = run;
    }
}

__global__ void scatter_ids(const int* __restrict__ lens, int* __restrict__ cursor,
                            int* __restrict__ sorted) {
    int w = blockIdx.x * blockDim.x + threadIdx.x;
    if (w >= 16384) return;
    int len = lens[w];
    if (len > 0) {
        int pos = atomicAdd(&cursor[len], 1);
        sorted[pos] = w;
    }
}

// ---------------- Kernel B: forward LSTM recurrence, 8 words/wave ----------------
__launch_bounds__(256, 2)
__global__ void bilstm_main(const int* __restrict__ chars, const float* __restrict__ w_hh,
                            const float4* __restrict__ xproj, const float* __restrict__ hbwd,
                            const int* __restrict__ sorted, const int* __restrict__ nvp,
                            float* __restrict__ out) {
    __shared__ float lds[16384];  // [k][j][gate] f32, 64KB
    const int nv = *nvp;
    if (blockIdx.x * 32 >= nv) return;  // whole block dead (uniform)
    const int tid = threadIdx.x;
    // stage W_hh transposed: lds[(k*64+j)*4+gate] = w_hh[gate*64+j][k]
    for (int i = tid; i < 16384; i += 256) {
        int row = i >> 6, k = i & 63;
        lds[(((k << 6) | (row & 63)) << 2) | (row >> 6)] = w_hh[i];
    }
    __syncthreads();

    const int wave = tid >> 6, lane = tid & 63;
    const int base = (blockIdx.x * 4 + wave) * 8;
    const int nw = min(8, nv - base);
    if (nw <= 0) return;  // no barriers after this point

    int idv = 0;
    if (lane < 8 && base + lane < nv) idv = sorted[base + lane];

    int wid[8], ch[8], len[8];
#pragma unroll
    for (int g = 0; g < 8; ++g) {
        wid[g] = __builtin_amdgcn_readlane(idv, g);
        int c = 0;
        if (lane < 32) c = chars[wid[g] * 32 + lane];
        ch[g] = c;
        unsigned long long m = __ballot(c != 0);
        len[g] = (g < nw) ? __popcll(m) : 0;
    }
    int maxlen = 0;
#pragma unroll
    for (int g = 0; g < 8; ++g) maxlen = max(maxlen, len[g]);

    float h[8], cc[8];
#pragma unroll
    for (int g = 0; g < 8; ++g) { h[g] = 0.0f; cc[g] = 0.0f; }

    const float4* ldsw = (const float4*)lds;  // index: k*64 + lane

    for (int t = 0; t < maxlen; ++t) {
        // input-projection lookups (L2-hot); ch beyond len is 0 -> defined bias row
        float4 xp[8];
#pragma unroll
        for (int g = 0; g < 8; ++g) {
            int ct = __builtin_amdgcn_readlane(ch[g], t);
            xp[g] = xproj[ct * 64 + lane];
        }
        float4 acc[8];
#pragma unroll
        for (int g = 0; g < 8; ++g) acc[g] = make_float4(0.f, 0.f, 0.f, 0.f);
        // recurrent matmul: one ds_read_b128 per k serves all 8 words
#pragma unroll 4
        for (int k = 0; k < 64; ++k) {
            float4 w4 = ldsw[(k << 6) + lane];
#pragma unroll
            for (int g = 0; g < 8; ++g) {
                float hk = rl_f(h[g], k);
                acc[g].x += hk * w4.x;
                acc[g].y += hk * w4.y;
                acc[g].z += hk * w4.z;
                acc[g].w += hk * w4.w;
            }
        }
#pragma unroll
        for (int g = 0; g < 8; ++g) {
            float gi = fast_sig(acc[g].x + xp[g].x);
            float gf = fast_sig(acc[g].y + xp[g].y);
            float gg = fast_tanh(acc[g].z + xp[g].z);
            float go = fast_sig(acc[g].w + xp[g].w);
            float cn = gf * cc[g] + gi * gg;
            float hn = go * fast_tanh(cn);
            bool act = (t < len[g]);  // wave-uniform
            cc[g] = act ? cn : cc[g];
            h[g] = act ? hn : h[g];
        }
    }

#pragma unroll
    for (int g = 0; g < 8; ++g) {
        if (g < nw) {
            int cl = __builtin_amdgcn_readlane(ch[g], len[g] - 1);
            float hb = hbwd[cl * 64 + lane];
            out[wid[g] * 128 + lane] = h[g];
            out[wid[g] * 128 + 64 + lane] = hb;
        }
    }
}

extern "C" void kernel_launch(void* const* d_in, const int* in_sizes, int n_in,
                              void* d_out, int out_size, void* d_ws, size_t ws_size,
                              hipStream_t stream) {
    const int* chars    = (const int*)d_in[0];
    const float* emb    = (const float*)d_in[1];
    const float* w_ih_f = (const float*)d_in[2];
    const float* w_hh_f = (const float*)d_in[3];
    const float* b_ih_f = (const float*)d_in[4];
    const float* b_hh_f = (const float*)d_in[5];
    const float* w_ih_b = (const float*)d_in[6];
    // d_in[7] = w_hh_b: unused (backward runs one step from zero state)
    const float* b_ih_b = (const float*)d_in[8];
    const float* b_hh_b = (const float*)d_in[9];
    float* out = (float*)d_out;

    float* wsf   = (float*)d_ws;
    float* xproj = wsf;                    // 65536 f32 (256KB)
    float* hbwd  = wsf + 65536;            // 16384 f32 (64KB)
    int* iws     = (int*)(wsf + 65536 + 16384);
    int* lens    = iws;                    // 16384
    int* sorted  = iws + 16384;            // 16384
    int* cnt     = iws + 32768;            // 33
    int* cursor  = iws + 32801;            // 33
    int* nv      = iws + 32834;            // 1

    hipMemsetAsync(d_out, 0, (size_t)out_size * sizeof(float), stream);
    hipMemsetAsync(cnt, 0, 33 * sizeof(int), stream);
    build_tables<<<256, 64, 0, stream>>>(emb, w_ih_f, b_ih_f, b_hh_f,
                                         w_ih_b, b_ih_b, b_hh_b, xproj, hbwd);
    count_lens<<<64, 256, 0, stream>>>(chars, lens, cnt);
    scan_buckets<<<1, 64, 0, stream>>>(cnt, cursor, nv);
    scatter_ids<<<64, 256, 0, stream>>>(lens, cursor, sorted);
    bilstm_main<<<512, 256, 0, stream>>>(chars, w_hh_f, (const float4*)xproj,
                                         hbwd, sorted, nv, out);
}

// Round 3
// 195.376 us; speedup vs baseline: 1.1647x; 1.1647x over previous
//
#include <hip/hip_runtime.h>
#include <hip/hip_bf16.h>
#include <stdint.h>

#define LOG2E 1.4426950408889634f

__device__ __forceinline__ float fast_sig(float x) {
    float e = __builtin_amdgcn_exp2f(-LOG2E * x);
    return __builtin_amdgcn_rcpf(1.0f + e);
}
__device__ __forceinline__ float fast_tanh(float x) {
    float e = __builtin_amdgcn_exp2f(2.0f * LOG2E * x);
    return 1.0f - 2.0f * __builtin_amdgcn_rcpf(e + 1.0f);
}
__device__ __forceinline__ float rl_f(float v, int k) {
    return __int_as_float(__builtin_amdgcn_readlane(__float_as_int(v), k));
}

// ---------------- Kernel A: per-char-value tables + W_hh transpose ----------------
// xproj[v][j] = float4 gate pre-acts (i,f,g,o) of unit j from char v (incl. both biases)
// hbwd[v][j]  = backward-direction output for last-char value v
// wt[k*256 + j*4 + g] = w_hh_f[(g*64+j)*64 + k]   (so main staging is linear)
__global__ void build_tables(const float* __restrict__ emb,
                             const float* __restrict__ w_ih_f, const float* __restrict__ b_ih_f,
                             const float* __restrict__ b_hh_f,
                             const float* __restrict__ w_ih_b, const float* __restrict__ b_ih_b,
                             const float* __restrict__ b_hh_b,
                             const float* __restrict__ w_hh_f,
                             float* __restrict__ xproj, float* __restrict__ hbwd,
                             float* __restrict__ wt) {
    int v = blockIdx.x;   // 0..255
    int j = threadIdx.x;  // 0..63
    // transpose one element of W_hh (16384 threads total)
    int d = v * 64 + j;
    int tk = d >> 8, tj = (d >> 2) & 63, tg = d & 3;
    wt[d] = w_hh_f[(((tg << 6) | tj) << 6) | tk];

    float e[20];
#pragma unroll
    for (int t = 0; t < 20; ++t) e[t] = emb[v * 20 + t];
    float sf[4], sb[4];
#pragma unroll
    for (int g = 0; g < 4; ++g) {
        int row = g * 64 + j;
        float a = b_ih_f[row] + b_hh_f[row];
        float b = b_ih_b[row] + b_hh_b[row];
#pragma unroll
        for (int t = 0; t < 20; ++t) {
            a += e[t] * w_ih_f[row * 20 + t];
            b += e[t] * w_ih_b[row * 20 + t];
        }
        sf[g] = a; sb[g] = b;
    }
    ((float4*)xproj)[v * 64 + j] = make_float4(sf[0], sf[1], sf[2], sf[3]);
    float cb = fast_sig(sb[0]) * fast_tanh(sb[2]);
    hbwd[v * 64 + j] = fast_sig(sb[3]) * fast_tanh(cb);
}

// ---------------- Prepass: length bucketing ----------------
__global__ void count_lens(const int* __restrict__ chars, int* __restrict__ lens,
                           int* __restrict__ cnt) {
    // 8 words per 256-thread block; 32 lanes per word -> coalesced 128B reads
    int word = blockIdx.x * 8 + (threadIdx.x >> 5);
    int c = threadIdx.x & 31;
    int v = chars[word * 32 + c];
    unsigned long long m = __ballot(v != 0);
    int hi = (threadIdx.x >> 5) & 1;
    int len = __popcll(m & (hi ? 0xFFFFFFFF00000000ULL : 0x00000000FFFFFFFFULL));
    if (c == 0) {
        lens[word] = len;
        if (len > 0) atomicAdd(&cnt[len], 1);
    }
}

__global__ void scan_buckets(const int* __restrict__ cnt, int* __restrict__ cursor,
                             int* __restrict__ nv) {
    if (threadIdx.x == 0) {
        int run = 0;
        for (int L = 1; L <= 32; ++L) { cursor[L] = run; run += cnt[L]; }
        *nv = run;
    }
}

__global__ void scatter_ids(const int* __restrict__ lens, int* __restrict__ cursor,
                            int* __restrict__ sorted) {
    int w = blockIdx.x * blockDim.x + threadIdx.x;
    if (w >= 16384) return;
    int len = lens[w];
    if (len > 0) {
        int pos = atomicAdd(&cursor[len], 1);
        sorted[pos] = w;
    }
}

// ---------------- Kernel B: forward LSTM recurrence, 4 words/wave ----------------
__launch_bounds__(256, 2)
__global__ void bilstm_main(const int* __restrict__ chars, const float4* __restrict__ wt,
                            const float4* __restrict__ xproj, const float* __restrict__ hbwd,
                            const int* __restrict__ sorted, const int* __restrict__ nvp,
                            float* __restrict__ out) {
    __shared__ float4 ldsw[4096];  // [k][j] float4 gates, 64KB
    const int nv = *nvp;
    if (blockIdx.x * 16 >= nv) return;  // whole block dead (uniform)
    const int tid = threadIdx.x;
    // linear, coalesced, conflict-free staging of pre-transposed W_hh
    for (int i = tid; i < 4096; i += 256) ldsw[i] = wt[i];
    __syncthreads();

    const int wave = tid >> 6, lane = tid & 63;
    const int base = (blockIdx.x * 4 + wave) * 4;
    const int nw = min(4, nv - base);
    if (nw <= 0) return;  // no barriers after this point

    int idv = 0;
    if (lane < 4 && base + lane < nv) idv = sorted[base + lane];

    int wid[4], ch[4], len[4];
#pragma unroll
    for (int g = 0; g < 4; ++g) {
        wid[g] = __builtin_amdgcn_readlane(idv, g);
        int c = 0;
        if (lane < 32) c = chars[wid[g] * 32 + lane];
        ch[g] = c;
        unsigned long long m = __ballot(c != 0);
        len[g] = (g < nw) ? __popcll(m) : 0;
    }
    int maxlen = 0;
#pragma unroll
    for (int g = 0; g < 4; ++g) maxlen = max(maxlen, len[g]);

    float h[4], cc[4];
#pragma unroll
    for (int g = 0; g < 4; ++g) { h[g] = 0.0f; cc[g] = 0.0f; }

    for (int t = 0; t < maxlen; ++t) {
        float4 xp[4];
#pragma unroll
        for (int g = 0; g < 4; ++g) {
            int ct = __builtin_amdgcn_readlane(ch[g], t);
            xp[g] = xproj[ct * 64 + lane];
        }
        float4 acc[4];
#pragma unroll
        for (int g = 0; g < 4; ++g) acc[g] = make_float4(0.f, 0.f, 0.f, 0.f);
#pragma unroll 8
        for (int k = 0; k < 64; ++k) {
            float4 w4 = ldsw[(k << 6) + lane];
#pragma unroll
            for (int g = 0; g < 4; ++g) {
                float hk = rl_f(h[g], k);
                acc[g].x = fmaf(hk, w4.x, acc[g].x);
                acc[g].y = fmaf(hk, w4.y, acc[g].y);
                acc[g].z = fmaf(hk, w4.z, acc[g].z);
                acc[g].w = fmaf(hk, w4.w, acc[g].w);
            }
        }
#pragma unroll
        for (int g = 0; g < 4; ++g) {
            float gi = fast_sig(acc[g].x + xp[g].x);
            float gf = fast_sig(acc[g].y + xp[g].y);
            float gg = fast_tanh(acc[g].z + xp[g].z);
            float go = fast_sig(acc[g].w + xp[g].w);
            float cn = gf * cc[g] + gi * gg;
            float hn = go * fast_tanh(cn);
            bool act = (t < len[g]);  // wave-uniform
            cc[g] = act ? cn : cc[g];
            h[g] = act ? hn : h[g];
        }
    }

#pragma unroll
    for (int g = 0; g < 4; ++g) {
        if (g < nw) {
            int cl = __builtin_amdgcn_readlane(ch[g], len[g] - 1);
            float hb = hbwd[cl * 64 + lane];
            out[wid[g] * 128 + lane] = h[g];
            out[wid[g] * 128 + 64 + lane] = hb;
        }
    }
}

extern "C" void kernel_launch(void* const* d_in, const int* in_sizes, int n_in,
                              void* d_out, int out_size, void* d_ws, size_t ws_size,
                              hipStream_t stream) {
    const int* chars    = (const int*)d_in[0];
    const float* emb    = (const float*)d_in[1];
    const float* w_ih_f = (const float*)d_in[2];
    const float* w_hh_f = (const float*)d_in[3];
    const float* b_ih_f = (const float*)d_in[4];
    const float* b_hh_f = (const float*)d_in[5];
    const float* w_ih_b = (const float*)d_in[6];
    // d_in[7] = w_hh_b: unused (backward runs one step from zero state)
    const float* b_ih_b = (const float*)d_in[8];
    const float* b_hh_b = (const float*)d_in[9];
    float* out = (float*)d_out;

    float* wsf   = (float*)d_ws;
    float* xproj = wsf;                    // 65536 f32 (256KB)
    float* hbwd  = wsf + 65536;            // 16384 f32 (64KB)
    float* wt    = wsf + 65536 + 16384;    // 16384 f32 (64KB) transposed W_hh
    int* iws     = (int*)(wt + 16384);
    int* lens    = iws;                    // 16384
    int* sorted  = iws + 16384;            // 16384
    int* cnt     = iws + 32768;            // 33
    int* cursor  = iws + 32801;            // 33
    int* nv      = iws + 32834;            // 1

    (void)hipMemsetAsync(d_out, 0, (size_t)out_size * sizeof(float), stream);
    (void)hipMemsetAsync(cnt, 0, 33 * sizeof(int), stream);
    build_tables<<<256, 64, 0, stream>>>(emb, w_ih_f, b_ih_f, b_hh_f,
                                         w_ih_b, b_ih_b, b_hh_b, w_hh_f,
                                         xproj, hbwd, wt);
    count_lens<<<2048, 256, 0, stream>>>(chars, lens, cnt);
    scan_buckets<<<1, 64, 0, stream>>>(cnt, cursor, nv);
    scatter_ids<<<64, 256, 0, stream>>>(lens, cursor, sorted);
    bilstm_main<<<1024, 256, 0, stream>>>(chars, (const float4*)wt,
                                          (const float4*)xproj,
                                          hbwd, sorted, nv, out);
}